// Round 5
// baseline (100.469 us; speedup 1.0000x reference)
//
#include <hip/hip_runtime.h>
#include <math.h>

#define L 16384
#define H 128
#define P 256
#define CL 32
#define NCH (L/CL)   // 512 chunks
#define GS 16        // chunks per group
#define NG (NCH/GS)  // 32 groups
#define KDIM 512     // out-GEMM K = [x2re | x2im]
#define NBU 512      // bu-GEMM N  = [BuRe | BuIm]

typedef __attribute__((ext_vector_type(8))) short short8;   // 8 bf16
typedef __attribute__((ext_vector_type(4))) float f32x4;

__device__ inline unsigned short f2bf(float f){          // fp32 -> bf16 RNE
  union { float f; unsigned u; } v; v.f = f;
  unsigned u = v.u;
  u += 0x7fffu + ((u >> 16) & 1u);
  return (unsigned short)(u >> 16);
}
__device__ inline float bf2f(unsigned short s){
  union { unsigned u; float f; } v; v.u = ((unsigned)s) << 16;
  return v.f;
}

struct Params { float M11,M12,M21,M22,s1,s2; };

__device__ inline Params get_params(const float* A_diag, const float* steps, int p){
  float A = A_diag[p]; A = A > 0.f ? A : 0.f;          // relu
  float dt = 1.f/(1.f + expf(-steps[p]));              // sigmoid
  float schur = 1.f/(1.f + dt*dt*A);
  Params q;
  q.M11 = 1.f - dt*dt*A*schur;
  q.M12 = -dt*A*schur;
  q.M21 = dt*schur;
  q.M22 = schur;
  q.s1 = q.M11*dt;
  q.s2 = q.M21*dt;
  return q;
}

// Relaxed agent-scope atomics: no buffer_inv / buffer_wbl2 cache maintenance.
__device__ inline unsigned long long aload(const unsigned long long* p){
  return __hip_atomic_load((unsigned long long*)p, __ATOMIC_RELAXED,
                           __HIP_MEMORY_SCOPE_AGENT);
}
__device__ inline void apub(unsigned long long* p, unsigned long long v){
  (void)__hip_atomic_exchange(p, v, __ATOMIC_RELAXED, __HIP_MEMORY_SCOPE_AGENT);
}
__device__ inline void fpub(unsigned* p){
  (void)__hip_atomic_exchange(p, 1u, __ATOMIC_RELAXED, __HIP_MEMORY_SCOPE_AGENT);
}
__device__ inline void wait_flag(unsigned* f){
  while (__hip_atomic_load(f, __ATOMIC_RELAXED, __HIP_MEMORY_SCOPE_AGENT) == 0u)
    __builtin_amdgcn_s_sleep(2);
}

// ---- K0: weight swizzles + flag clear (256 blocks x 512) --------------------
__global__ __launch_bounds__(512) void prep_w(const float* __restrict__ B,
                                              const float* __restrict__ Cw,
                                              unsigned short* __restrict__ BWswz,
                                              unsigned short* __restrict__ Bswz,
                                              unsigned* __restrict__ flags){
  int gidx = blockIdx.x*512 + threadIdx.x;
  if (gidx < NCH + NG) flags[gidx] = 0u;       // 544 flags (visible at kernel end)
  if (gidx < H*NBU){                           // BW swizzle (k=h 0..127, n 0..511)
    int k = gidx >> 9, n = gidx & 511;
    int p = n & 255, c2 = n >> 8;
    float v = B[((size_t)p*H + k)*2 + c2];
    BWswz[((size_t)(k>>3)*NBU + n)*8 + (k&7)] = f2bf(v);
  } else {                                     // C swizzle (k 0..511, n=h 0..127)
    int g2 = gidx - H*NBU;
    int k = g2 >> 7, n = g2 & 127;
    float v = (k < P) ? Cw[((size_t)n*P + k)*2]
                      : -Cw[((size_t)n*P + (k-P))*2 + 1];
    Bswz[((size_t)(k>>3)*H + n)*8 + (k&7)] = f2bf(v);
  }
}

// ---- K1: fully fused; per-block flag sync, data via MALL exchanges ----------
// All 512 blocks co-resident (2 blocks/CU: 33.3KB LDS, <=128 VGPR) so spins
// cannot deadlock (proven R2-R4).
__global__ __launch_bounds__(512, 4) void linoss_fused(
    const float* __restrict__ in,      // (L,H) fp32
    const float* __restrict__ A_diag,  // (P,)
    const float* __restrict__ steps,   // (P,)
    const float* __restrict__ Dv,      // (H,)
    const unsigned short* __restrict__ BWswz,
    const unsigned short* __restrict__ Bswz,
    unsigned long long* __restrict__ finals, // [2][NCH][P] float2-as-u64
    unsigned long long* __restrict__ gfin,   // [2][NG][P]  float2-as-u64
    unsigned* __restrict__ flag1,      // [NCH]
    unsigned* __restrict__ flag2,      // [NG]
    float* __restrict__ out)           // (L,H) fp32
{
  __shared__ unsigned short sX[CL][NBU+8];   // Bu (bf16), overwritten in place by x2
  const int c   = blockIdx.x;
  const int tid = threadIdx.x;

  // ---------------- Phase B: chunk Bu via MFMA (fp32 load, bf16 in-reg) --------
  {
    int lane = tid & 63, w = tid >> 6;
    int ml = lane & 15, quad = lane >> 4;
    int mt = w & 1, ng = w >> 1;
    int lm0 = mt*16;
    const float* aptr = in + (size_t)(c*CL + lm0 + ml)*H + quad*8;
    short8 av[4];
    #pragma unroll
    for (int ks=0; ks<4; ks++){
      float4 f0 = *(const float4*)(aptr + ks*32);
      float4 f1 = *(const float4*)(aptr + ks*32 + 4);
      union { short8 s; unsigned short u[8]; } o;
      o.u[0]=f2bf(f0.x); o.u[1]=f2bf(f0.y); o.u[2]=f2bf(f0.z); o.u[3]=f2bf(f0.w);
      o.u[4]=f2bf(f1.x); o.u[5]=f2bf(f1.y); o.u[6]=f2bf(f1.z); o.u[7]=f2bf(f1.w);
      av[ks] = o.s;
    }
    f32x4 acc[8];
    #pragma unroll
    for (int t=0;t<8;t++) acc[t] = (f32x4){0.f,0.f,0.f,0.f};
    #pragma unroll
    for (int ks=0; ks<4; ks++){
      #pragma unroll
      for (int t=0;t<8;t++){
        int n0 = (ng*8 + t)*16;
        short8 bv = *(const short8*)(BWswz + ((size_t)(ks*4+quad)*NBU + n0 + ml)*8);
        acc[t] = __builtin_amdgcn_mfma_f32_16x16x32_bf16(av[ks], bv, acc[t], 0, 0, 0);
      }
    }
    #pragma unroll
    for (int t=0;t<8;t++){
      int n = (ng*8+t)*16 + ml;
      #pragma unroll
      for (int r=0;r<4;r++)
        sX[lm0 + quad*4 + r][n] = f2bf(acc[t][r]);
    }
  }
  __syncthreads();

  // ---------------- Phase B2: local chunk scan -> publish own final ------------
  const int p = tid & 255, part = tid >> 8;
  Params q = get_params(A_diag, steps, p);
  float Ta=q.M11, Tb=q.M12, Tc=q.M21, Td=q.M22;     // T = M^32
  #pragma unroll
  for (int s=0;s<5;s++){
    float na=Ta*Ta+Tb*Tc, nb=Ta*Tb+Tb*Td, nc=Tc*Ta+Td*Tc, nd=Tc*Tb+Td*Td;
    Ta=na;Tb=nb;Tc=nc;Td=nd;
  }
  float fx1=0.f, fx2=0.f;                            // this chunk's final
  {
    #pragma unroll
    for (int i=0;i<CL;i++){
      float u = bf2f(sX[i][part*256 + p]);
      float n1 = q.M11*fx1 + q.M12*fx2 + q.s1*u;
      float n2 = q.M21*fx1 + q.M22*fx2 + q.s2*u;
      fx1 = n1; fx2 = n2;
    }
    union { unsigned long long u; float2 f; } w; w.f = make_float2(fx1,fx2);
    apub(&finals[(size_t)(part*NCH + c)*P + p], w.u);
  }
  asm volatile("s_waitcnt vmcnt(0)" ::: "memory");   // publish drained per-thread
  __syncthreads();                                   // all 512 words at MALL
  if (tid == 0) fpub(&flag1[c]);

  const int g = c >> 4, iw = c & (GS-1);
  const unsigned long long* Fp = finals + (size_t)part*NCH*P + (size_t)g*GS*P + p;

  // ---------------- Phase C: group producer (iw==15) ---------------------------
  float z1=0.f, z2v=0.f;            // exclusive in-group mate prefix (chain T)
  bool have_z = false;
  if (iw == GS-1){
    if (tid < GS-1) wait_flag(&flag1[g*GS + tid]);   // 15 scalar flag polls
    __syncthreads();
    unsigned long long v[GS-1];
    #pragma unroll
    for (int j=0;j<GS-1;j++) v[j] = aload(Fp + (size_t)j*P);
    #pragma unroll
    for (int j=0;j<GS-1;j++){
      union { unsigned long long u; float2 f; } w; w.u = v[j];
      float n1 = Ta*z1 + Tb*z2v + w.f.x;
      float n2 = Tc*z1 + Td*z2v + w.f.y;
      z1=n1; z2v=n2;
    }
    have_z = true;
    float t1 = Ta*z1 + Tb*z2v + fx1;                 // group total
    float t2 = Tc*z1 + Td*z2v + fx2;
    union { unsigned long long u; float2 f; } w; w.f = make_float2(t1,t2);
    apub(&gfin[(size_t)(part*NG + g)*P + p], w.u);
    asm volatile("s_waitcnt vmcnt(0)" ::: "memory");
    __syncthreads();
    if (tid == 0) fpub(&flag2[g]);
  }

  // ---------------- wave-uniform carry matrices (overlap with others' waits) ---
  float sa=1.f, sb=0.f, sc=0.f, sd=1.f;              // S = T^iw
  {
    float wa=Ta, wb=Tb, wc=Tc, wd=Td;
    #pragma unroll
    for (int bit=0; bit<4; bit++){
      if ((iw>>bit)&1){
        float na = wa*sa + wb*sc, nb = wa*sb + wb*sd;
        float nc = wc*sa + wd*sc, nd = wc*sb + wd*sd;
        sa=na; sb=nb; sc=nc; sd=nd;
      }
      float qa = wa*wa + wb*wc, qb = wa*wb + wb*wd;
      float qc = wc*wa + wd*wc, qd = wc*wb + wd*wd;
      wa=qa; wb=qb; wc=qc; wd=qd;
    }
  }
  float ga=Ta, gb=Tb, gc=Tc, gd=Td;                  // T_G = T^16
  #pragma unroll
  for (int s=0;s<4;s++){
    float na=ga*ga+gb*gc, nb=ga*gb+gb*gd, nc=gc*ga+gd*gc, nd=gc*gb+gd*gd;
    ga=na;gb=nb;gc=nc;gd=nd;
  }

  // ---------------- Consumer flag waits: <=31 group + <=15 mate scalars --------
  if (tid < g)                             wait_flag(&flag2[tid]);
  if (!have_z && tid >= 64 && tid < 64+iw) wait_flag(&flag1[g*GS + (tid-64)]);
  __syncthreads();

  // ---------------- Phase D: carries + in-LDS scan -----------------------------
  {
    // Y_g = combine gfin[0..g-1], batched-8 loads (all ready, no polling)
    float y1=0.f, y2=0.f;
    {
      const unsigned long long* Gp = gfin + (size_t)part*NG*P + p;
      for (int t0=0; t0<g; t0+=8){
        unsigned long long v[8];
        #pragma unroll
        for (int j=0;j<8;j++){
          int jj = t0+j;
          v[j] = (jj < g) ? aload(Gp + (size_t)jj*P) : 0ULL;
        }
        #pragma unroll
        for (int j=0;j<8;j++){
          int jj = t0+j;
          if (jj < g){
            union { unsigned long long u; float2 f; } w; w.u = v[j];
            float n1 = ga*y1 + gb*y2 + w.f.x;
            float n2 = gc*y1 + gd*y2 + w.f.y;
            y1=n1; y2=n2;
          }
        }
      }
    }
    // z = exclusive mate prefix (producers already have it)
    if (!have_z){
      for (int t0=0; t0<iw; t0+=8){
        unsigned long long v[8];
        #pragma unroll
        for (int j=0;j<8;j++){
          int jj = t0+j;
          v[j] = (jj < iw) ? aload(Fp + (size_t)jj*P) : 0ULL;
        }
        #pragma unroll
        for (int j=0;j<8;j++){
          int jj = t0+j;
          if (jj < iw){
            union { unsigned long long u; float2 f; } w; w.u = v[j];
            float n1 = Ta*z1 + Tb*z2v + w.f.x;
            float n2 = Tc*z1 + Td*z2v + w.f.y;
            z1=n1; z2v=n2;
          }
        }
      }
    }
    float x1 = sa*y1 + sb*y2 + z1;
    float x2 = sc*y1 + sd*y2 + z2v;
    // in-LDS scan: overwrite sX column with bf16(x2)
    #pragma unroll
    for (int i=0;i<CL;i++){
      float u = bf2f(sX[i][part*256 + p]);
      float n1 = q.M11*x1 + q.M12*x2 + q.s1*u;
      float n2 = q.M21*x1 + q.M22*x2 + q.s2*u;
      x1 = n1; x2 = n2;
      sX[i][part*256 + p] = f2bf(x2);
    }
  }
  __syncthreads();

  // ---------------- out GEMM: 32 rows x 128 h ----------------------------------
  {
    int lane = tid & 63, w = tid >> 6;
    int ml = lane & 15, quad = lane >> 4;
    int mt = w & 1;
    int ntb = (w >> 1) * 2;
    f32x4 acc[2];
    acc[0] = (f32x4){0.f,0.f,0.f,0.f};
    acc[1] = (f32x4){0.f,0.f,0.f,0.f};
    for (int ks=0; ks<KDIM/32; ks++){
      short8 av = *(const short8*)&sX[mt*16 + ml][ks*32 + quad*8];
      #pragma unroll
      for (int j=0;j<2;j++){
        short8 bv = *(const short8*)(Bswz + ((size_t)(ks*4+quad)*H + (ntb+j)*16 + ml)*8);
        acc[j] = __builtin_amdgcn_mfma_f32_16x16x32_bf16(av, bv, acc[j], 0, 0, 0);
      }
    }
    #pragma unroll
    for (int j=0;j<2;j++){
      int h = (ntb+j)*16 + ml;
      float dv = Dv[h];
      #pragma unroll
      for (int r=0;r<4;r++){
        int l = c*CL + mt*16 + quad*4 + r;
        out[(size_t)l*H + h] = acc[j][r] + in[(size_t)l*H + h]*dv;
      }
    }
  }
}

extern "C" void kernel_launch(void* const* d_in, const int* in_sizes, int n_in,
                              void* d_out, int out_size, void* d_ws, size_t ws_size,
                              hipStream_t stream) {
  const float* in     = (const float*)d_in[0];   // (L,H)
  const float* A_diag = (const float*)d_in[1];   // (P,)
  const float* B      = (const float*)d_in[2];   // (P,H,2)
  const float* Cw     = (const float*)d_in[3];   // (H,P,2)
  const float* Dv     = (const float*)d_in[4];   // (H,)
  const float* steps  = (const float*)d_in[5];   // (P,)
  float* out = (float*)d_out;

  unsigned short* BWswz = (unsigned short*)d_ws;             // 128*512 bf16 (128KB)
  unsigned short* Bswz  = BWswz + (size_t)H*NBU;             // 512*128 bf16 (128KB)
  unsigned long long* finals = (unsigned long long*)(Bswz + (size_t)KDIM*H); // [2][NCH][P]
  unsigned long long* gfin   = finals + (size_t)2*NCH*P;     // [2][NG][P]
  unsigned* flags = (unsigned*)(gfin + (size_t)2*NG*P);      // 544 flags
  unsigned* flag1 = flags;                                   // [512]
  unsigned* flag2 = flags + NCH;                             // [32]

  prep_w<<<256, 512, 0, stream>>>(B, Cw, BWswz, Bswz, flags);
  linoss_fused<<<NCH, 512, 0, stream>>>(in, A_diag, steps, Dv, BWswz, Bswz,
                                        finals, gfin, flag1, flag2, out);
}

// Round 6
// 94.365 us; speedup vs baseline: 1.0647x; 1.0647x over previous
//
#include <hip/hip_runtime.h>
#include <math.h>

#define L 16384
#define H 128
#define P 256
#define CL 64
#define NCH (L/CL)   // 256 chunks
#define GS 16        // chunks per group
#define NG (NCH/GS)  // 16 groups
#define KDIM 512     // out-GEMM K = [x2re | x2im]
#define NBU 512      // bu-GEMM N  = [BuRe | BuIm]

typedef __attribute__((ext_vector_type(8))) short short8;   // 8 bf16
typedef __attribute__((ext_vector_type(4))) float f32x4;

__device__ inline unsigned short f2bf(float f){          // fp32 -> bf16 RNE
  union { float f; unsigned u; } v; v.f = f;
  unsigned u = v.u;
  u += 0x7fffu + ((u >> 16) & 1u);
  return (unsigned short)(u >> 16);
}
__device__ inline float bf2f(unsigned short s){
  union { unsigned u; float f; } v; v.u = ((unsigned)s) << 16;
  return v.f;
}

struct Params { float M11,M12,M21,M22,s1,s2; };

__device__ inline Params get_params(const float* A_diag, const float* steps, int p){
  float A = A_diag[p]; A = A > 0.f ? A : 0.f;          // relu
  float dt = 1.f/(1.f + expf(-steps[p]));              // sigmoid
  float schur = 1.f/(1.f + dt*dt*A);
  Params q;
  q.M11 = 1.f - dt*dt*A*schur;
  q.M12 = -dt*A*schur;
  q.M21 = dt*schur;
  q.M22 = schur;
  q.s1 = q.M11*dt;
  q.s2 = q.M21*dt;
  return q;
}

// Relaxed agent-scope atomics: no buffer_inv / buffer_wbl2 cache maintenance.
__device__ inline unsigned long long aload(const unsigned long long* p){
  return __hip_atomic_load((unsigned long long*)p, __ATOMIC_RELAXED,
                           __HIP_MEMORY_SCOPE_AGENT);
}
__device__ inline void apub(unsigned long long* p, unsigned long long v){
  (void)__hip_atomic_exchange(p, v, __ATOMIC_RELAXED, __HIP_MEMORY_SCOPE_AGENT);
}
__device__ inline void fpub(unsigned* p){
  (void)__hip_atomic_exchange(p, 1u, __ATOMIC_RELAXED, __HIP_MEMORY_SCOPE_AGENT);
}
__device__ inline void wait_flag(unsigned* f){
  while (__hip_atomic_load(f, __ATOMIC_RELAXED, __HIP_MEMORY_SCOPE_AGENT) == 0u)
    __builtin_amdgcn_s_sleep(1);
}

// ---- K0: weight swizzles + flag clear (256 blocks x 512) --------------------
__global__ __launch_bounds__(512) void prep_w(const float* __restrict__ B,
                                              const float* __restrict__ Cw,
                                              unsigned short* __restrict__ BWswz,
                                              unsigned short* __restrict__ Bswz,
                                              unsigned* __restrict__ flags){
  int gidx = blockIdx.x*512 + threadIdx.x;
  if (gidx < NCH + NG) flags[gidx] = 0u;       // 272 flags (visible at kernel end)
  if (gidx < H*NBU){                           // BW swizzle (k=h 0..127, n 0..511)
    int k = gidx >> 9, n = gidx & 511;
    int p = n & 255, c2 = n >> 8;
    float v = B[((size_t)p*H + k)*2 + c2];
    BWswz[((size_t)(k>>3)*NBU + n)*8 + (k&7)] = f2bf(v);
  } else {                                     // C swizzle (k 0..511, n=h 0..127)
    int g2 = gidx - H*NBU;
    int k = g2 >> 7, n = g2 & 127;
    float v = (k < P) ? Cw[((size_t)n*P + k)*2]
                      : -Cw[((size_t)n*P + (k-P))*2 + 1];
    Bswz[((size_t)(k>>3)*H + n)*8 + (k&7)] = f2bf(v);
  }
}

// ---- K1: fully fused, CL=64 rows/block, 256 blocks (1/CU, always resident) --
// Co-residency under ANY packing: LDS 66.6KB -> >=1 block/CU capacity, 256
// blocks <= 256 CUs. Spin-waits cannot deadlock.
__global__ __launch_bounds__(512, 2) void linoss_fused(
    const float* __restrict__ in,      // (L,H) fp32
    const float* __restrict__ A_diag,  // (P,)
    const float* __restrict__ steps,   // (P,)
    const float* __restrict__ Dv,      // (H,)
    const unsigned short* __restrict__ BWswz,
    const unsigned short* __restrict__ Bswz,
    unsigned long long* __restrict__ finals, // [2][NCH][P] float2-as-u64
    unsigned long long* __restrict__ gfin,   // [2][NG][P]  float2-as-u64
    unsigned* __restrict__ flag1,      // [NCH]
    unsigned* __restrict__ flag2,      // [NG]
    float* __restrict__ out)           // (L,H) fp32
{
  __shared__ unsigned short sX[CL][NBU+8];   // 66.6 KB; Bu, overwritten by x2
  const int c   = blockIdx.x;
  const int tid = threadIdx.x;

  // ---------------- Phase B: chunk Bu via MFMA (fp32 load, bf16 in-reg) --------
  {
    int lane = tid & 63, w = tid >> 6;
    int ml = lane & 15, quad = lane >> 4;
    int rt = w & 3, ch = w >> 2;             // row-tile 0..3, col-half 0..1
    int lm0 = rt*16;
    const float* aptr = in + (size_t)(c*CL + lm0 + ml)*H + quad*8;
    short8 av[4];
    #pragma unroll
    for (int ks=0; ks<4; ks++){
      float4 f0 = *(const float4*)(aptr + ks*32);
      float4 f1 = *(const float4*)(aptr + ks*32 + 4);
      union { short8 s; unsigned short u[8]; } o;
      o.u[0]=f2bf(f0.x); o.u[1]=f2bf(f0.y); o.u[2]=f2bf(f0.z); o.u[3]=f2bf(f0.w);
      o.u[4]=f2bf(f1.x); o.u[5]=f2bf(f1.y); o.u[6]=f2bf(f1.z); o.u[7]=f2bf(f1.w);
      av[ks] = o.s;
    }
    f32x4 acc[16];
    #pragma unroll
    for (int t=0;t<16;t++) acc[t] = (f32x4){0.f,0.f,0.f,0.f};
    #pragma unroll
    for (int ks=0; ks<4; ks++){
      #pragma unroll
      for (int t=0;t<16;t++){
        int n0 = ch*256 + t*16;
        short8 bv = *(const short8*)(BWswz + ((size_t)(ks*4+quad)*NBU + n0 + ml)*8);
        acc[t] = __builtin_amdgcn_mfma_f32_16x16x32_bf16(av[ks], bv, acc[t], 0, 0, 0);
      }
    }
    #pragma unroll
    for (int t=0;t<16;t++){
      int n = ch*256 + t*16 + ml;
      #pragma unroll
      for (int r=0;r<4;r++)
        sX[lm0 + quad*4 + r][n] = f2bf(acc[t][r]);
    }
  }
  __syncthreads();

  // ---------------- Phase B2: local chunk scan -> publish own final ------------
  const int p = tid & 255, part = tid >> 8;
  Params q = get_params(A_diag, steps, p);
  float Ta=q.M11, Tb=q.M12, Tc=q.M21, Td=q.M22;     // T = M^64
  #pragma unroll
  for (int s=0;s<6;s++){
    float na=Ta*Ta+Tb*Tc, nb=Ta*Tb+Tb*Td, nc=Tc*Ta+Td*Tc, nd=Tc*Tb+Td*Td;
    Ta=na;Tb=nb;Tc=nc;Td=nd;
  }
  float fx1=0.f, fx2=0.f;                            // this chunk's final
  {
    #pragma unroll
    for (int i=0;i<CL;i++){
      float u = bf2f(sX[i][part*256 + p]);
      float n1 = q.M11*fx1 + q.M12*fx2 + q.s1*u;
      float n2 = q.M21*fx1 + q.M22*fx2 + q.s2*u;
      fx1 = n1; fx2 = n2;
    }
    union { unsigned long long u; float2 f; } w; w.f = make_float2(fx1,fx2);
    apub(&finals[(size_t)(part*NCH + c)*P + p], w.u);
  }
  asm volatile("s_waitcnt vmcnt(0)" ::: "memory");   // publish drained per-thread
  __syncthreads();
  if (tid == 0) fpub(&flag1[c]);

  const int g = c >> 4, iw = c & (GS-1);
  const unsigned long long* Fp = finals + (size_t)part*NCH*P + (size_t)g*GS*P + p;

  // ---------------- Phase C: group producer (iw==15) ---------------------------
  float z1=0.f, z2v=0.f;            // exclusive in-group mate prefix (chain T)
  bool have_z = false;
  if (iw == GS-1){
    if (tid < GS-1) wait_flag(&flag1[g*GS + tid]);   // 15 scalar flag polls
    __syncthreads();
    unsigned long long v[GS-1];
    #pragma unroll
    for (int j=0;j<GS-1;j++) v[j] = aload(Fp + (size_t)j*P);
    #pragma unroll
    for (int j=0;j<GS-1;j++){
      union { unsigned long long u; float2 f; } w; w.u = v[j];
      float n1 = Ta*z1 + Tb*z2v + w.f.x;
      float n2 = Tc*z1 + Td*z2v + w.f.y;
      z1=n1; z2v=n2;
    }
    have_z = true;
    float t1 = Ta*z1 + Tb*z2v + fx1;                 // group total
    float t2 = Tc*z1 + Td*z2v + fx2;
    union { unsigned long long u; float2 f; } w; w.f = make_float2(t1,t2);
    apub(&gfin[(size_t)(part*NG + g)*P + p], w.u);
    asm volatile("s_waitcnt vmcnt(0)" ::: "memory");
    __syncthreads();
    if (tid == 0) fpub(&flag2[g]);
  }

  // ---------------- wave-uniform carry matrices (overlap with others' waits) ---
  float sa=1.f, sb=0.f, sc=0.f, sd=1.f;              // S = T^iw
  {
    float wa=Ta, wb=Tb, wc=Tc, wd=Td;
    #pragma unroll
    for (int bit=0; bit<4; bit++){
      if ((iw>>bit)&1){
        float na = wa*sa + wb*sc, nb = wa*sb + wb*sd;
        float nc = wc*sa + wd*sc, nd = wc*sb + wd*sd;
        sa=na; sb=nb; sc=nc; sd=nd;
      }
      float qa = wa*wa + wb*wc, qb = wa*wb + wb*wd;
      float qc = wc*wa + wd*wc, qd = wc*wb + wd*wd;
      wa=qa; wb=qb; wc=qc; wd=qd;
    }
  }
  float ga=Ta, gb=Tb, gc=Tc, gd=Td;                  // T_G = T^16
  #pragma unroll
  for (int s=0;s<4;s++){
    float na=ga*ga+gb*gc, nb=ga*gb+gb*gd, nc=gc*ga+gd*gc, nd=gc*gb+gd*gd;
    ga=na;gb=nb;gc=nc;gd=nd;
  }

  // ---------------- Consumer flag waits: <=15 group + <=15 mate scalars --------
  if (tid < g)                             wait_flag(&flag2[tid]);
  if (!have_z && tid >= 64 && tid < 64+iw) wait_flag(&flag1[g*GS + (tid-64)]);
  __syncthreads();

  // ---------------- Phase D: carries + in-LDS scan -----------------------------
  {
    // Issue ALL remote loads (Y rows + mate rows) as one static batch, then chain
    const unsigned long long* Gp = gfin + (size_t)part*NG*P + p;
    unsigned long long vy[NG-1], vm[GS-1];
    #pragma unroll
    for (int j=0;j<NG-1;j++) vy[j] = (j < g) ? aload(Gp + (size_t)j*P) : 0ULL;
    if (!have_z){
      #pragma unroll
      for (int j=0;j<GS-1;j++) vm[j] = (j < iw) ? aload(Fp + (size_t)j*P) : 0ULL;
    }
    float y1=0.f, y2=0.f;
    #pragma unroll
    for (int j=0;j<NG-1;j++){
      if (j < g){
        union { unsigned long long u; float2 f; } w; w.u = vy[j];
        float n1 = ga*y1 + gb*y2 + w.f.x;
        float n2 = gc*y1 + gd*y2 + w.f.y;
        y1=n1; y2=n2;
      }
    }
    if (!have_z){
      #pragma unroll
      for (int j=0;j<GS-1;j++){
        if (j < iw){
          union { unsigned long long u; float2 f; } w; w.u = vm[j];
          float n1 = Ta*z1 + Tb*z2v + w.f.x;
          float n2 = Tc*z1 + Td*z2v + w.f.y;
          z1=n1; z2v=n2;
        }
      }
    }
    float x1 = sa*y1 + sb*y2 + z1;
    float x2 = sc*y1 + sd*y2 + z2v;
    // in-LDS scan: overwrite sX column with bf16(x2)
    #pragma unroll
    for (int i=0;i<CL;i++){
      float u = bf2f(sX[i][part*256 + p]);
      float n1 = q.M11*x1 + q.M12*x2 + q.s1*u;
      float n2 = q.M21*x1 + q.M22*x2 + q.s2*u;
      x1 = n1; x2 = n2;
      sX[i][part*256 + p] = f2bf(x2);
    }
  }
  __syncthreads();

  // ---------------- out GEMM: 64 rows x 128 h ----------------------------------
  {
    int lane = tid & 63, w = tid >> 6;
    int ml = lane & 15, quad = lane >> 4;
    int rt2 = w & 3;                         // row-tile 0..3
    int nh  = w >> 2;                        // n-half 0..1 (4 n-tiles each)
    f32x4 acc[4];
    #pragma unroll
    for (int j=0;j<4;j++) acc[j] = (f32x4){0.f,0.f,0.f,0.f};
    for (int ks=0; ks<KDIM/32; ks++){
      short8 av = *(const short8*)&sX[rt2*16 + ml][ks*32 + quad*8];
      #pragma unroll
      for (int j=0;j<4;j++){
        short8 bv = *(const short8*)(Bswz + ((size_t)(ks*4+quad)*H + (nh*4+j)*16 + ml)*8);
        acc[j] = __builtin_amdgcn_mfma_f32_16x16x32_bf16(av, bv, acc[j], 0, 0, 0);
      }
    }
    #pragma unroll
    for (int j=0;j<4;j++){
      int h = (nh*4+j)*16 + ml;
      float dv = Dv[h];
      #pragma unroll
      for (int r=0;r<4;r++){
        int l = c*CL + rt2*16 + quad*4 + r;
        out[(size_t)l*H + h] = acc[j][r] + in[(size_t)l*H + h]*dv;
      }
    }
  }
}

extern "C" void kernel_launch(void* const* d_in, const int* in_sizes, int n_in,
                              void* d_out, int out_size, void* d_ws, size_t ws_size,
                              hipStream_t stream) {
  const float* in     = (const float*)d_in[0];   // (L,H)
  const float* A_diag = (const float*)d_in[1];   // (P,)
  const float* B      = (const float*)d_in[2];   // (P,H,2)
  const float* Cw     = (const float*)d_in[3];   // (H,P,2)
  const float* Dv     = (const float*)d_in[4];   // (H,)
  const float* steps  = (const float*)d_in[5];   // (P,)
  float* out = (float*)d_out;

  unsigned short* BWswz = (unsigned short*)d_ws;             // 128*512 bf16 (128KB)
  unsigned short* Bswz  = BWswz + (size_t)H*NBU;             // 512*128 bf16 (128KB)
  unsigned long long* finals = (unsigned long long*)(Bswz + (size_t)KDIM*H); // [2][NCH][P]
  unsigned long long* gfin   = finals + (size_t)2*NCH*P;     // [2][NG][P]
  unsigned* flags = (unsigned*)(gfin + (size_t)2*NG*P);      // 272 flags
  unsigned* flag1 = flags;                                   // [256]
  unsigned* flag2 = flags + NCH;                             // [16]

  prep_w<<<256, 512, 0, stream>>>(B, Cw, BWswz, Bswz, flags);
  linoss_fused<<<NCH, 512, 0, stream>>>(in, A_diag, steps, Dv, BWswz, Bswz,
                                        finals, gfin, flag1, flag2, out);
}